// Round 4
// baseline (694.686 us; speedup 1.0000x reference)
//
#include <hip/hip_runtime.h>

// Flash cross-attention, B=32, Tq=512, Tk=2048, D=512, fp32 in/out.
// Round 7 = round-5 design, third submission (2x container infra failure,
// no kernel verdict; kernel re-audited for hang/fault paths: none found).
//  - MQ 32 -> 16: 1024 blocks, LDS 37 KB, launch_bounds(256,4) -> 4 blocks/CU
//    (16 waves/CU, ~2x round-4 occupancy).
//  - Softmax fully lane-local: lane owns q-row l16, keys quad*4..+4; two
//    shfl_xor reductions; m/l/alpha lane-local.
//  - Defer-max (T13): skip acc rescale + alpha exp when __all(mx <= m+8).
//  - Q-side hi/lo split, fragment-major KfL, Vt[d][k], 2 barriers/tile
//    pipeline, setprio on MFMA carried from round 4.

#define BATCH 32
#define TQ 512
#define TK 2048
#define DIM 512
#define MQ 16
#define NK 16
#define NKT (TK / NK)   // 128 k-tiles

typedef __attribute__((ext_vector_type(8))) _Float16 half8;
typedef __attribute__((ext_vector_type(2))) _Float16 half2v;
typedef __attribute__((ext_vector_type(4))) float float4v;
typedef __attribute__((ext_vector_type(4))) unsigned int uint4v;

__device__ __forceinline__ half2v pkrtz(float a, float b) {
  auto r = __builtin_amdgcn_cvt_pkrtz(a, b);  // __fp16 x2
  half2v o;
  o[0] = (_Float16)r[0];
  o[1] = (_Float16)r[1];
  return o;
}

__device__ __forceinline__ unsigned int pkrtz_u32(float a, float b) {
  half2v h = pkrtz(a, b);
  return __builtin_bit_cast(unsigned int, h);
}

__global__ __launch_bounds__(256, 4)
void attn_flash6(const float* __restrict__ dec, const float* __restrict__ enc,
                 float* __restrict__ out) {
  const int id = blockIdx.x;
  const int b = ((id & 7) << 2) + ((id >> 3) & 3);  // XCD-clustered batches
  const int q0 = (id >> 5) * MQ;
  const int tid = threadIdx.x;
  const int wave = tid >> 6;
  const int lane = tid & 63;
  const int quad = lane >> 4;
  const int l16 = lane & 15;

  // K tile fragment-major (RNE f16): chunk sg (d=32sg..+32), slot quad*16+key
  // holds K[key][32sg+8*quad .. +8].
  __shared__ __align__(16) _Float16 KfL[16 * 64 * 8];   // 16 KB
  __shared__ __align__(16) _Float16 VtL[DIM * NK];      // 16 KB, Vt[d][k]
  __shared__ __align__(16) float Sp[4][MQ][20];         // 5 KB (padded rows)

  // ---- Q fragments: hi/lo split over this wave's d-quarter, row q0+l16 ----
  half8 qhi[4], qlo[4];
  {
    const float* qrow =
        dec + ((size_t)b * TQ + (q0 + l16)) * DIM + wave * 128 + quad * 8;
#pragma unroll
    for (int s = 0; s < 4; ++s) {
      float4v v0 = *(const float4v*)(qrow + s * 32);
      float4v v1 = *(const float4v*)(qrow + s * 32 + 4);
#pragma unroll
      for (int j = 0; j < 4; ++j) {
        float f0 = v0[j], f1 = v1[j];
        _Float16 h0 = (_Float16)f0;   // RNE
        _Float16 h1 = (_Float16)f1;
        qhi[s][j] = h0;
        qhi[s][j + 4] = h1;
        qlo[s][j] = (_Float16)(f0 - (float)h0);
        qlo[s][j + 4] = (_Float16)(f1 - (float)h1);
      }
    }
  }

  float4v acc[8];
#pragma unroll
  for (int t = 0; t < 8; ++t) acc[t] = float4v{0.f, 0.f, 0.f, 0.f};

  // per-lane online-softmax state for q-row l16 (redundant across quads)
  float m_r = -INFINITY, l_r = 0.0f;

  const float* encb = enc + (size_t)b * TK * DIM;
  const int key = tid & 15;
  const int drow = tid >> 4;           // dbase = drow*8 + i*128
  const int sgb = drow >> 2;           // chunk base
  const int slot = ((drow & 3) << 4) + key;

  float4v pf[8];
  half8 nxt[4];

  // ---- prologue: tile 0 -> regs -> convert -> KfL + nxt ----
  {
    const float* kp = encb + (size_t)key * DIM + drow * 8;
#pragma unroll
    for (int i = 0; i < 4; ++i) {
      pf[2 * i] = *(const float4v*)(kp + i * 128);
      pf[2 * i + 1] = *(const float4v*)(kp + i * 128 + 4);
    }
#pragma unroll
    for (int i = 0; i < 4; ++i) {
      half8 h;
#pragma unroll
      for (int j = 0; j < 4; ++j) {
        h[j] = (_Float16)pf[2 * i][j];          // RNE
        h[j + 4] = (_Float16)pf[2 * i + 1][j];
      }
      *(half8*)&KfL[((sgb + i * 4) * 64 + slot) * 8] = h;
      nxt[i] = h;
    }
  }
  __syncthreads();

  for (int kt = 0; kt < NKT; ++kt) {
    // ================= phase 1 =================
    // issue global loads for tile kt+1 (wraps; harmless re-read)
    {
      const int k0n = ((kt + 1) & (NKT - 1)) * NK;
      const float* kp = encb + (size_t)(k0n + key) * DIM + drow * 8;
#pragma unroll
      for (int i = 0; i < 4; ++i) {
        pf[2 * i] = *(const float4v*)(kp + i * 128);
        pf[2 * i + 1] = *(const float4v*)(kp + i * 128 + 4);
      }
    }
    // Vt write for tile kt (from regs staged last iter)
#pragma unroll
    for (int i = 0; i < 4; ++i) {
      const int dbase = drow * 8 + i * 128;
#pragma unroll
      for (int j = 0; j < 8; ++j) VtL[(dbase + j) * NK + key] = nxt[i][j];
    }
    // QK^T over this wave's d-quarter: (Qhi + Qlo) x K
    {
      float4v s0 = float4v{0.f, 0.f, 0.f, 0.f};
      __builtin_amdgcn_s_setprio(1);
#pragma unroll
      for (int s = 0; s < 4; ++s) {
        half8 kf = *(const half8*)&KfL[(((wave << 2) + s) * 64 + lane) * 8];
        s0 = __builtin_amdgcn_mfma_f32_16x16x32_f16(qhi[s], kf, s0, 0, 0, 0);
        s0 = __builtin_amdgcn_mfma_f32_16x16x32_f16(qlo[s], kf, s0, 0, 0, 0);
      }
      __builtin_amdgcn_s_setprio(0);
#pragma unroll
      for (int r = 0; r < 4; ++r) {
        Sp[wave][(quad << 2) + r][l16] = s0[r];
      }
    }
    __syncthreads();

    // ================= phase 2 =================
    // lane-local softmax: lane owns q-row l16, keys quad*4..+4 (all waves
    // redundant). Row-reduce = shfl_xor(16) + shfl_xor(32).
    half8 pB;
    {
      const int kb = quad << 2;
      float4v sa = float4v{0.f, 0.f, 0.f, 0.f};
#pragma unroll
      for (int w = 0; w < 4; ++w) {
        sa += *(const float4v*)&Sp[w][l16][kb];
      }
      float mx = fmaxf(fmaxf(sa[0], sa[1]), fmaxf(sa[2], sa[3]));
      mx = fmaxf(mx, __shfl_xor(mx, 16));
      mx = fmaxf(mx, __shfl_xor(mx, 32));  // full row max (16 keys)
      // defer-max: only rescale when the row max actually grew past THR=8
      if (!__all(mx <= m_r + 8.0f)) {
        const float mnew = fmaxf(m_r, mx);
        const float al = __expf(m_r - mnew);
        m_r = mnew;
        l_r *= al;
#pragma unroll
        for (int t = 0; t < 8; ++t) acc[t] *= al;
      }
      float p[4];
      float sum = 0.0f;
#pragma unroll
      for (int c = 0; c < 4; ++c) {
        p[c] = __expf(sa[c] - m_r);
        sum += p[c];
      }
      sum += __shfl_xor(sum, 16);
      sum += __shfl_xor(sum, 32);          // full row sum
      l_r += sum;

      // assemble PV B-frag: lane(quad,l16) needs P[row l16][keys quad*8..+8]
      // (quads 2,3 feed the zero upper-K half).
      unsigned int w0 = pkrtz_u32(p[0], p[1]);
      unsigned int w1 = pkrtz_u32(p[2], p[3]);
      unsigned int pw0 = __shfl_xor(w0, 16);   // partner quad^1's 4 keys
      unsigned int pw1 = __shfl_xor(w1, 16);
      // octet for this quad-pair: [even-quad 4 keys, odd-quad 4 keys]
      unsigned int a0 = (quad & 1) ? pw0 : w0;
      unsigned int a1 = (quad & 1) ? pw1 : w1;
      unsigned int a2 = (quad & 1) ? w0 : pw0;
      unsigned int a3 = (quad & 1) ? w1 : pw1;
      // quads 0,1 hold keys 0..8; quads 2,3 hold keys 8..16
      unsigned int b0 = __shfl_xor(a0, 32);
      unsigned int b1 = __shfl_xor(a1, 32);
      unsigned int b2 = __shfl_xor(a2, 32);
      unsigned int b3 = __shfl_xor(a3, 32);
      uint4v pw;
      if (quad == 0) {
        pw = uint4v{a0, a1, a2, a3};
      } else if (quad == 1) {
        pw = uint4v{b0, b1, b2, b3};        // from quad 3: keys 8..16
      } else {
        pw = uint4v{0u, 0u, 0u, 0u};
      }
      pB = __builtin_bit_cast(half8, pw);
    }

    // PV^T: acc = V^T x P^T (A = V^T from VtL, B = P from regs)
    {
      half8 hz;
#pragma unroll
      for (int j = 0; j < 8; ++j) hz[j] = (_Float16)0.0f;
      __builtin_amdgcn_s_setprio(1);
#pragma unroll
      for (int t = 0; t < 8; ++t) {
        const int dd = wave * 128 + t * 16 + l16;
        half8 vf = hz;
        if (quad < 2) vf = *(const half8*)&VtL[dd * NK + quad * 8];
        acc[t] = __builtin_amdgcn_mfma_f32_16x16x32_f16(vf, pB, acc[t], 0, 0, 0);
      }
      __builtin_amdgcn_s_setprio(0);
    }

    // convert tile kt+1 and write KfL (QK(kt) readers are past barrier 1)
#pragma unroll
    for (int i = 0; i < 4; ++i) {
      half8 h;
#pragma unroll
      for (int j = 0; j < 4; ++j) {
        h[j] = (_Float16)pf[2 * i][j];          // RNE
        h[j + 4] = (_Float16)pf[2 * i + 1][j];
      }
      *(half8*)&KfL[((sgb + i * 4) * 64 + slot) * 8] = h;
      nxt[i] = h;
    }
    __syncthreads();
  }

  // ---- epilogue: O = O^T normalized; l_r is already full-row per lane ----
  const float linv = 1.0f / l_r;
  float* orow =
      out + ((size_t)b * TQ + (q0 + l16)) * DIM + wave * 128 + quad * 4;
#pragma unroll
  for (int t = 0; t < 8; ++t) {
    float4v o = acc[t] * linv;
    *(float4v*)(orow + t * 16) = o;
  }
}

extern "C" void kernel_launch(void* const* d_in, const int* in_sizes, int n_in,
                              void* d_out, int out_size, void* d_ws, size_t ws_size,
                              hipStream_t stream) {
  const float* dec = (const float*)d_in[0];
  const float* enc = (const float*)d_in[1];
  float* out = (float*)d_out;
  attn_flash6<<<dim3(BATCH * (TQ / MQ)), 256, 0, stream>>>(dec, enc, out);
}

// Round 5
// 418.841 us; speedup vs baseline: 1.6586x; 1.6586x over previous
//
#include <hip/hip_runtime.h>

// Flash cross-attention, B=32, Tq=512, Tk=2048, D=512, fp32 in/out.
// Round 8: revert to MQ=32 (round-1 shape), cut LDS traffic + serial softmax.
//  - Vt row stride 20 halfs (40 B): u16 transpose-writes ~2-way (free) instead
//    of 8-way; PV reads become conflict-free b64.
//  - PV via mfma_f32_16x16x16_f16 (K=16, no zero padding): B-frag is the
//    lane's own 4 softmax p-values -> no cross-lane P assembly at all;
//    all 4 quads carry V data; PV MFMA cycles halve.
//  - Lane-parallel softmax at MQ=32: lane owns rows (l16, 16+l16), keys
//    quad*4..+4; reduce = shfl_xor(16)+shfl_xor(32). Defer-max (T13) kept.
//  - Q-side hi/lo split QK (16x16x32), fragment-major KfL, reg prefetch,
//    2 barriers/tile, setprio on MFMA: carried from round 1.

#define BATCH 32
#define TQ 512
#define TK 2048
#define DIM 512
#define MQ 32
#define NK 16
#define NKT (TK / NK)   // 128 k-tiles
#define VSTR 20         // Vt row stride in halfs (40 B)

typedef __attribute__((ext_vector_type(8))) _Float16 half8;
typedef __attribute__((ext_vector_type(4))) _Float16 half4;
typedef __attribute__((ext_vector_type(2))) _Float16 half2v;
typedef __attribute__((ext_vector_type(4))) float float4v;

__device__ __forceinline__ half2v pkrtz(float a, float b) {
  auto r = __builtin_amdgcn_cvt_pkrtz(a, b);  // __fp16 x2
  half2v o;
  o[0] = (_Float16)r[0];
  o[1] = (_Float16)r[1];
  return o;
}

__global__ __launch_bounds__(256, 2)
void attn_flash8(const float* __restrict__ dec, const float* __restrict__ enc,
                 float* __restrict__ out) {
  const int id = blockIdx.x;
  const int b = ((id & 7) << 2) + ((id >> 3) & 3);  // XCD-clustered batches
  const int q0 = (id >> 5) * MQ;
  const int tid = threadIdx.x;
  const int wave = tid >> 6;
  const int lane = tid & 63;
  const int quad = lane >> 4;
  const int l16 = lane & 15;

  // K tile fragment-major (RNE f16): chunk sg (d=32sg..+32), slot quad*16+key
  // holds K[key][32sg+8*quad .. +8].
  __shared__ __align__(16) _Float16 KfL[16 * 64 * 8];   // 16 KB
  __shared__ __align__(16) _Float16 VtL[DIM * VSTR];    // 20 KB, Vt[d][k] str 20
  __shared__ __align__(16) float Sp[4][MQ][20];         // 10 KB (padded rows)

  // ---- Q fragments: hi/lo split, 2 m-tiles, this wave's d-quarter ----
  half8 qhi[2][4], qlo[2][4];
#pragma unroll
  for (int mt = 0; mt < 2; ++mt) {
    const float* qrow =
        dec + ((size_t)b * TQ + (q0 + mt * 16 + l16)) * DIM + wave * 128 + quad * 8;
#pragma unroll
    for (int s = 0; s < 4; ++s) {
      float4v v0 = *(const float4v*)(qrow + s * 32);
      float4v v1 = *(const float4v*)(qrow + s * 32 + 4);
#pragma unroll
      for (int j = 0; j < 4; ++j) {
        float f0 = v0[j], f1 = v1[j];
        _Float16 h0 = (_Float16)f0;   // RNE
        _Float16 h1 = (_Float16)f1;
        qhi[mt][s][j] = h0;
        qhi[mt][s][j + 4] = h1;
        qlo[mt][s][j] = (_Float16)(f0 - (float)h0);
        qlo[mt][s][j + 4] = (_Float16)(f1 - (float)h1);
      }
    }
  }

  float4v acc[2][8];
#pragma unroll
  for (int mt = 0; mt < 2; ++mt)
#pragma unroll
    for (int t = 0; t < 8; ++t) acc[mt][t] = float4v{0.f, 0.f, 0.f, 0.f};

  // per-lane softmax state: row l16 (m0,l0) and row 16+l16 (m1,l1)
  float m0 = -INFINITY, l0 = 0.0f;
  float m1 = -INFINITY, l1 = 0.0f;

  const float* encb = enc + (size_t)b * TK * DIM;
  const int key = tid & 15;
  const int drow = tid >> 4;           // dbase = drow*8 + i*128
  const int sgb = drow >> 2;           // chunk base
  const int slot = ((drow & 3) << 4) + key;

  float4v pf[8];
  half8 nxt[4];

  // ---- prologue: tile 0 -> regs -> convert -> KfL + nxt ----
  {
    const float* kp = encb + (size_t)key * DIM + drow * 8;
#pragma unroll
    for (int i = 0; i < 4; ++i) {
      pf[2 * i] = *(const float4v*)(kp + i * 128);
      pf[2 * i + 1] = *(const float4v*)(kp + i * 128 + 4);
    }
#pragma unroll
    for (int i = 0; i < 4; ++i) {
      half8 h;
#pragma unroll
      for (int j = 0; j < 4; ++j) {
        h[j] = (_Float16)pf[2 * i][j];          // RNE
        h[j + 4] = (_Float16)pf[2 * i + 1][j];
      }
      *(half8*)&KfL[((sgb + i * 4) * 64 + slot) * 8] = h;
      nxt[i] = h;
    }
  }
  __syncthreads();

  for (int kt = 0; kt < NKT; ++kt) {
    // ================= phase 1 =================
    // issue global loads for tile kt+1 (wraps; harmless re-read)
    {
      const int k0n = ((kt + 1) & (NKT - 1)) * NK;
      const float* kp = encb + (size_t)(k0n + key) * DIM + drow * 8;
#pragma unroll
      for (int i = 0; i < 4; ++i) {
        pf[2 * i] = *(const float4v*)(kp + i * 128);
        pf[2 * i + 1] = *(const float4v*)(kp + i * 128 + 4);
      }
    }
    // Vt write for tile kt (from regs staged last iter); stride-20 rows ->
    // bank = 16*(quad&1) + j*10 + key>>1 : ~2-way, free
#pragma unroll
    for (int i = 0; i < 4; ++i) {
      const int dbase = drow * 8 + i * 128;
#pragma unroll
      for (int j = 0; j < 8; ++j) VtL[(dbase + j) * VSTR + key] = nxt[i][j];
    }
    // QK^T over this wave's d-quarter: (Qhi + Qlo) x K, 2 m-tiles
    {
      float4v s0 = float4v{0.f, 0.f, 0.f, 0.f};
      float4v s1 = float4v{0.f, 0.f, 0.f, 0.f};
      __builtin_amdgcn_s_setprio(1);
#pragma unroll
      for (int s = 0; s < 4; ++s) {
        half8 kf = *(const half8*)&KfL[(((wave << 2) + s) * 64 + lane) * 8];
        s0 = __builtin_amdgcn_mfma_f32_16x16x32_f16(qhi[0][s], kf, s0, 0, 0, 0);
        s0 = __builtin_amdgcn_mfma_f32_16x16x32_f16(qlo[0][s], kf, s0, 0, 0, 0);
        s1 = __builtin_amdgcn_mfma_f32_16x16x32_f16(qhi[1][s], kf, s1, 0, 0, 0);
        s1 = __builtin_amdgcn_mfma_f32_16x16x32_f16(qlo[1][s], kf, s1, 0, 0, 0);
      }
      __builtin_amdgcn_s_setprio(0);
#pragma unroll
      for (int r = 0; r < 4; ++r) {
        Sp[wave][(quad << 2) + r][l16] = s0[r];
        Sp[wave][16 + (quad << 2) + r][l16] = s1[r];
      }
    }
    __syncthreads();

    // ================= phase 2 =================
    // lane-parallel softmax (redundant per wave): lane owns rows (l16, 16+l16),
    // keys quad*4..+4. Row-reduce = shfl_xor(16) + shfl_xor(32).
    half4 pB0, pB1;
    {
      const int kb = quad << 2;
      float4v sa = float4v{0.f, 0.f, 0.f, 0.f};
      float4v sb = float4v{0.f, 0.f, 0.f, 0.f};
#pragma unroll
      for (int w = 0; w < 4; ++w) {
        sa += *(const float4v*)&Sp[w][l16][kb];
        sb += *(const float4v*)&Sp[w][16 + l16][kb];
      }
      float mx0 = fmaxf(fmaxf(sa[0], sa[1]), fmaxf(sa[2], sa[3]));
      float mx1 = fmaxf(fmaxf(sb[0], sb[1]), fmaxf(sb[2], sb[3]));
      mx0 = fmaxf(mx0, __shfl_xor(mx0, 16));
      mx0 = fmaxf(mx0, __shfl_xor(mx0, 32));
      mx1 = fmaxf(mx1, __shfl_xor(mx1, 16));
      mx1 = fmaxf(mx1, __shfl_xor(mx1, 32));
      // defer-max (T13): rescale only when a row max grew past THR=8
      if (!__all(mx0 <= m0 + 8.0f && mx1 <= m1 + 8.0f)) {
        const float mn0 = fmaxf(m0, mx0);
        const float mn1 = fmaxf(m1, mx1);
        const float al0 = __expf(m0 - mn0);
        const float al1 = __expf(m1 - mn1);
        m0 = mn0; m1 = mn1;
        l0 *= al0; l1 *= al1;
#pragma unroll
        for (int t = 0; t < 8; ++t) {
          acc[0][t] *= al0;
          acc[1][t] *= al1;
        }
      }
      float p0[4], p1[4];
      float s0 = 0.0f, s1 = 0.0f;
#pragma unroll
      for (int c = 0; c < 4; ++c) {
        p0[c] = __expf(sa[c] - m0);
        s0 += p0[c];
        p1[c] = __expf(sb[c] - m1);
        s1 += p1[c];
      }
      s0 += __shfl_xor(s0, 16);
      s0 += __shfl_xor(s0, 32);
      s1 += __shfl_xor(s1, 16);
      s1 += __shfl_xor(s1, 32);
      l0 += s0;
      l1 += s1;
      // B-frag for 16x16x16 PV^T: lane(quad,l16) needs P[row][keys quad*4..+4]
      // == this lane's own p values. No shuffles.
      half2v a0 = pkrtz(p0[0], p0[1]);
      half2v a1 = pkrtz(p0[2], p0[3]);
      half2v b0v = pkrtz(p1[0], p1[1]);
      half2v b1v = pkrtz(p1[2], p1[3]);
      pB0[0] = a0[0]; pB0[1] = a0[1]; pB0[2] = a1[0]; pB0[3] = a1[1];
      pB1[0] = b0v[0]; pB1[1] = b0v[1]; pB1[2] = b1v[0]; pB1[3] = b1v[1];
    }

    // PV^T via 16x16x16: acc[mt] = V^T x P^T. A-frag = V^T[l16-row][quad*4..+4]
    // = b64 from VtL (stride 20 -> exactly-4-beat, conflict-free).
    {
      __builtin_amdgcn_s_setprio(1);
#pragma unroll
      for (int t = 0; t < 8; ++t) {
        const int dd = wave * 128 + t * 16 + l16;
        half4 vf = *(const half4*)&VtL[dd * VSTR + (quad << 2)];
        acc[0][t] = __builtin_amdgcn_mfma_f32_16x16x16f16(vf, pB0, acc[0][t], 0, 0, 0);
        acc[1][t] = __builtin_amdgcn_mfma_f32_16x16x16f16(vf, pB1, acc[1][t], 0, 0, 0);
      }
      __builtin_amdgcn_s_setprio(0);
    }

    // convert tile kt+1 and write KfL (QK(kt) readers are past barrier 1)
#pragma unroll
    for (int i = 0; i < 4; ++i) {
      half8 h;
#pragma unroll
      for (int j = 0; j < 4; ++j) {
        h[j] = (_Float16)pf[2 * i][j];          // RNE
        h[j + 4] = (_Float16)pf[2 * i + 1][j];
      }
      *(half8*)&KfL[((sgb + i * 4) * 64 + slot) * 8] = h;
      nxt[i] = h;
    }
    __syncthreads();
  }

  // ---- epilogue: O^T frag -> contiguous float4 stores along d ----
  // D[quad*4+r][l16]: lane's q-row = q0 + mt*16 + l16; d = wave*128+t*16+quad*4+r
  const float linv0 = 1.0f / l0;
  const float linv1 = 1.0f / l1;
#pragma unroll
  for (int mt = 0; mt < 2; ++mt) {
    const float linv = mt ? linv1 : linv0;
    float* orow =
        out + ((size_t)b * TQ + (q0 + mt * 16 + l16)) * DIM + wave * 128 + (quad << 2);
#pragma unroll
    for (int t = 0; t < 8; ++t) {
      float4v o = acc[mt][t] * linv;
      *(float4v*)(orow + t * 16) = o;
    }
  }
}

extern "C" void kernel_launch(void* const* d_in, const int* in_sizes, int n_in,
                              void* d_out, int out_size, void* d_ws, size_t ws_size,
                              hipStream_t stream) {
  const float* dec = (const float*)d_in[0];
  const float* enc = (const float*)d_in[1];
  float* out = (float*)d_out;
  attn_flash8<<<dim3(BATCH * (TQ / MQ)), 256, 0, stream>>>(dec, enc, out);
}